// Round 1
// baseline (304.640 us; speedup 1.0000x reference)
//
#include <hip/hip_runtime.h>
#include <hip/hip_bf16.h>
#include <stdint.h>

// GraphSAGE layer fused pipeline for MI355X (gfx950).
// Pipeline: cvt(x->bf16) | hist(deg) | scan(offsets) | csr fill | fused main
// (gather-mean + bf16 MFMA GEMM + relu + residual + bias).

typedef __bf16 bf16x8 __attribute__((ext_vector_type(8)));
typedef float f32x4 __attribute__((ext_vector_type(4)));

__device__ __forceinline__ unsigned short f2bf(float f) {
  unsigned int u = __float_as_uint(f);
  u += 0x7FFFu + ((u >> 16) & 1u);   // RNE
  return (unsigned short)(u >> 16);
}
__device__ __forceinline__ float bf2f(unsigned short b) {
  return __uint_as_float(((unsigned int)b) << 16);
}

// ---- convert x (fp32) -> xb (bf16), vectorized float4 ----
__global__ void k_cvt(const float* __restrict__ x, unsigned short* __restrict__ xb,
                      int total4) {
  int i = blockIdx.x * blockDim.x + threadIdx.x;
  if (i < total4) {
    const float4 v = ((const float4*)x)[i];
    ushort4 o;
    o.x = f2bf(v.x); o.y = f2bf(v.y); o.z = f2bf(v.z); o.w = f2bf(v.w);
    ((ushort4*)xb)[i] = o;
  }
}

// ---- degree histogram ----
__global__ void k_hist(const int* __restrict__ dst, int* __restrict__ deg, int e) {
  int i = blockIdx.x * blockDim.x + threadIdx.x;
  if (i < e) atomicAdd(&deg[dst[i]], 1);
}

// ---- exclusive scan, 3 kernels (N=100k -> 391 block sums <= 1024) ----
__global__ void k_scan1(const int* __restrict__ deg, int* __restrict__ offsets,
                        int* __restrict__ blksum, int n) {
  __shared__ int sc[256];
  int t = threadIdx.x;
  int i = blockIdx.x * 256 + t;
  int d = (i < n) ? deg[i] : 0;
  sc[t] = d;
  __syncthreads();
  for (int off = 1; off < 256; off <<= 1) {
    int v = (t >= off) ? sc[t - off] : 0;
    __syncthreads();
    sc[t] += v;
    __syncthreads();
  }
  if (i < n) offsets[i] = sc[t] - d;        // exclusive within block
  if (t == 255) blksum[blockIdx.x] = sc[255];
}

__global__ void k_scan2(const int* __restrict__ blksum, int* __restrict__ blkoff,
                        int nblk, int* __restrict__ offsets, int n, int e) {
  __shared__ int sc[1024];
  int t = threadIdx.x;
  int d = (t < nblk) ? blksum[t] : 0;
  sc[t] = d;
  __syncthreads();
  for (int off = 1; off < 1024; off <<= 1) {
    int v = (t >= off) ? sc[t - off] : 0;
    __syncthreads();
    sc[t] += v;
    __syncthreads();
  }
  if (t < nblk) blkoff[t] = sc[t] - d;
  if (t == 0) offsets[n] = e;               // total = E (all dst in [0,N))
}

__global__ void k_scan3(int* __restrict__ offsets, const int* __restrict__ blkoff, int n) {
  int i = blockIdx.x * blockDim.x + threadIdx.x;
  if (i < n) offsets[i] += blkoff[i >> 8];
}

// ---- CSR fill (order within a node arbitrary; sum is order-insensitive) ----
__global__ void k_fill(const int* __restrict__ src, const int* __restrict__ dst,
                       const int* __restrict__ offsets, int* __restrict__ cursor,
                       int* __restrict__ csr, int e) {
  int i = blockIdx.x * blockDim.x + threadIdx.x;
  if (i < e) {
    int d = dst[i];
    int p = atomicAdd(&cursor[d], 1);
    csr[offsets[d] + p] = src[i];
  }
}

// ---- fused main: 64-node tile per block, 4 waves ----
// LDS strides chosen for conflict-free ds_read_b128:
//   XT_S=72 bf16 = 36 dwords  -> bank (4*(m+q))%32, uniform 8 lanes/4-bank group
//   WF_S=136 bf16 = 68 dwords -> same property; rows 16B-aligned for b128.
#define XT_S 72
#define WF_S 136

__global__ __launch_bounds__(256) void k_main(
    const unsigned short* __restrict__ xb,
    const int* __restrict__ offsets, const int* __restrict__ csr,
    const float* __restrict__ W_fc, const float* __restrict__ b_fc,
    const float* __restrict__ W_res, const float* __restrict__ b_res,
    float* __restrict__ out, int n) {
  __shared__ unsigned short Xt[64 * XT_S];     // x tile, bf16
  __shared__ unsigned short Mt[64 * XT_S];     // mean tile, bf16
  __shared__ unsigned short WfcT[64 * WF_S];   // W_fc^T [n][k], k=0..127
  __shared__ unsigned short WresT[64 * XT_S];  // W_res^T [n][k], k=0..63

  const int tid = threadIdx.x;

  // Stage W transposed as bf16 (B-operand needs 8 contiguous k per lane).
  for (int i = tid; i < 64 * 128; i += 256) {
    int nc = i & 63, k = i >> 6;
    WfcT[nc * WF_S + k] = f2bf(W_fc[k * 64 + nc]);
  }
  for (int i = tid; i < 64 * 64; i += 256) {
    int nc = i & 63, k = i >> 6;
    WresT[nc * XT_S + k] = f2bf(W_res[k * 64 + nc]);
  }

  const int lane = tid & 63;
  const int w = tid >> 6;          // wave id: owns rows w*16..w*16+15
  const int quad = lane >> 4;      // 0..3
  const int m = lane & 15;
  const int tile0 = blockIdx.x * 64;

  // ---- gather phase: 4 edges in parallel (one per quad), bf16x4 per lane ----
  for (int i = 0; i < 16; ++i) {
    int lr = (w << 4) + i;
    int node = tile0 + lr;
    float s0 = 0.f, s1 = 0.f, s2 = 0.f, s3 = 0.f;
    int dg = 0;
    if (node < n) {
      int o0 = offsets[node];
      int o1 = offsets[node + 1];
      dg = o1 - o0;
      for (int eb = o0 + quad; eb < o1; eb += 4) {
        int sidx = csr[eb];
        ushort4 v = *(const ushort4*)(&xb[sidx * 64 + m * 4]);
        s0 += bf2f(v.x); s1 += bf2f(v.y); s2 += bf2f(v.z); s3 += bf2f(v.w);
      }
    }
    // reduce the 4 edge-subsets (lanes m, m+16, m+32, m+48)
    s0 += __shfl_xor(s0, 16); s0 += __shfl_xor(s0, 32);
    s1 += __shfl_xor(s1, 16); s1 += __shfl_xor(s1, 32);
    s2 += __shfl_xor(s2, 16); s2 += __shfl_xor(s2, 32);
    s3 += __shfl_xor(s3, 16); s3 += __shfl_xor(s3, 32);
    float inv = 1.0f / fmaxf((float)dg, 1.0f);
    if (quad == 0) {
      ushort4 mb;
      mb.x = f2bf(s0 * inv); mb.y = f2bf(s1 * inv);
      mb.z = f2bf(s2 * inv); mb.w = f2bf(s3 * inv);
      *(ushort4*)(&Mt[lr * XT_S + m * 4]) = mb;
    }
    Xt[lr * XT_S + lane] = (node < n) ? xb[node * 64 + lane] : (unsigned short)0;
  }
  __syncthreads();

  // ---- MFMA phase: wave w computes rows w*16..+15 x all 64 cols ----
  // A-frag: A[m=lane&15][k=quad*8+j] ; B-frag: B[k=quad*8+j][n=lane&15]
  const int arow = (w << 4) + m;
  bf16x8 aX0 = *(const bf16x8*)(&Xt[arow * XT_S + quad * 8]);
  bf16x8 aX1 = *(const bf16x8*)(&Xt[arow * XT_S + 32 + quad * 8]);
  bf16x8 aM0 = *(const bf16x8*)(&Mt[arow * XT_S + quad * 8]);
  bf16x8 aM1 = *(const bf16x8*)(&Mt[arow * XT_S + 32 + quad * 8]);

  f32x4 accu[4], accv[4];
  for (int nt = 0; nt < 4; ++nt) {
    const int nc = nt * 16 + m;
    bf16x8 b0 = *(const bf16x8*)(&WfcT[nc * WF_S + quad * 8]);
    bf16x8 b1 = *(const bf16x8*)(&WfcT[nc * WF_S + 32 + quad * 8]);
    bf16x8 b2 = *(const bf16x8*)(&WfcT[nc * WF_S + 64 + quad * 8]);
    bf16x8 b3 = *(const bf16x8*)(&WfcT[nc * WF_S + 96 + quad * 8]);
    f32x4 acc = {0.f, 0.f, 0.f, 0.f};
    acc = __builtin_amdgcn_mfma_f32_16x16x32_bf16(aX0, b0, acc, 0, 0, 0);
    acc = __builtin_amdgcn_mfma_f32_16x16x32_bf16(aX1, b1, acc, 0, 0, 0);
    acc = __builtin_amdgcn_mfma_f32_16x16x32_bf16(aM0, b2, acc, 0, 0, 0);
    acc = __builtin_amdgcn_mfma_f32_16x16x32_bf16(aM1, b3, acc, 0, 0, 0);
    accu[nt] = acc;
    bf16x8 c0 = *(const bf16x8*)(&WresT[nc * XT_S + quad * 8]);
    bf16x8 c1 = *(const bf16x8*)(&WresT[nc * XT_S + 32 + quad * 8]);
    f32x4 accr = {0.f, 0.f, 0.f, 0.f};
    accr = __builtin_amdgcn_mfma_f32_16x16x32_bf16(aX0, c0, accr, 0, 0, 0);
    accr = __builtin_amdgcn_mfma_f32_16x16x32_bf16(aX1, c1, accr, 0, 0, 0);
    accv[nt] = accr;
  }

  // ---- epilogue: C/D layout col=lane&15, row=quad*4+reg ----
  for (int nt = 0; nt < 4; ++nt) {
    const int nc = nt * 16 + m;
    const float bf = b_fc[nc];
    const float br = b_res[nc];
    for (int r = 0; r < 4; ++r) {
      int lr = (w << 4) + (quad << 2) + r;
      int node = tile0 + lr;
      if (node < n) {
        float u = fmaxf(accu[nt][r] + bf, 0.f);
        out[node * 64 + nc] = u + accv[nt][r] + br;
      }
    }
  }
}

extern "C" void kernel_launch(void* const* d_in, const int* in_sizes, int n_in,
                              void* d_out, int out_size, void* d_ws, size_t ws_size,
                              hipStream_t stream) {
  const float* x = (const float*)d_in[0];
  const int* src = (const int*)d_in[1];
  const int* dst = (const int*)d_in[2];
  const float* W_fc = (const float*)d_in[3];
  const float* b_fc = (const float*)d_in[4];
  const float* W_res = (const float*)d_in[5];
  const float* b_res = (const float*)d_in[6];
  float* out = (float*)d_out;
  const int n = in_sizes[0] / 64;
  const int e = in_sizes[1];

  // workspace layout (~17.3 MB total)
  char* ws = (char*)d_ws;
  int* deg = (int*)ws;        ws += (size_t)n * 4;
  int* offsets = (int*)ws;    ws += (size_t)(n + 1) * 4;
  int* blksum = (int*)ws;     ws += 1024 * 4;
  int* blkoff = (int*)ws;     ws += 1024 * 4;
  int* cursor = (int*)ws;     ws += (size_t)n * 4;
  int* csr = (int*)ws;        ws += (size_t)e * 4;
  ws = (char*)(((uintptr_t)ws + 15) & ~(uintptr_t)15);
  unsigned short* xb = (unsigned short*)ws;   // n*64 bf16

  hipMemsetAsync(deg, 0, (size_t)n * 4, stream);
  hipMemsetAsync(cursor, 0, (size_t)n * 4, stream);

  int total4 = in_sizes[0] / 4;
  k_cvt<<<(total4 + 255) / 256, 256, 0, stream>>>(x, xb, total4);
  k_hist<<<(e + 255) / 256, 256, 0, stream>>>(dst, deg, e);
  int nblk = (n + 255) / 256;
  k_scan1<<<nblk, 256, 0, stream>>>(deg, offsets, blksum, n);
  k_scan2<<<1, 1024, 0, stream>>>(blksum, blkoff, nblk, offsets, n, e);
  k_scan3<<<(n + 255) / 256, 256, 0, stream>>>(offsets, blkoff, n);
  k_fill<<<(e + 255) / 256, 256, 0, stream>>>(src, dst, offsets, cursor, csr, e);
  k_main<<<(n + 63) / 64, 256, 0, stream>>>(xb, offsets, csr, W_fc, b_fc, W_res,
                                            b_res, out, n);
}

// Round 2
// 195.724 us; speedup vs baseline: 1.5565x; 1.5565x over previous
//
#include <hip/hip_runtime.h>
#include <hip/hip_bf16.h>
#include <stdint.h>

// GraphSAGE layer fused pipeline for MI355X (gfx950), round 2.
// memset(deg) | k_prep(cvt+hist+Wcvt) | k_scan1 | k_scan2b | k_fill | k_main

typedef __bf16 bf16x8 __attribute__((ext_vector_type(8)));
typedef float f32x4 __attribute__((ext_vector_type(4)));

__device__ __forceinline__ unsigned short f2bf(float f) {
  unsigned int u = __float_as_uint(f);
  u += 0x7FFFu + ((u >> 16) & 1u);   // RNE
  return (unsigned short)(u >> 16);
}

// ---- fused prep: x->bf16, degree histogram, W^T -> bf16 ----
__global__ void k_prep(const float* __restrict__ x, unsigned short* __restrict__ xb,
                       int total4,
                       const int* __restrict__ dst, int* __restrict__ deg, int e,
                       const float* __restrict__ W_fc, unsigned short* __restrict__ WfcT_g,
                       const float* __restrict__ W_res, unsigned short* __restrict__ WresT_g) {
  int i = blockIdx.x * 256 + threadIdx.x;
  if (i < total4) {
    const float4 v = ((const float4*)x)[i];
    ushort4 o;
    o.x = f2bf(v.x); o.y = f2bf(v.y); o.z = f2bf(v.z); o.w = f2bf(v.w);
    ((ushort4*)xb)[i] = o;
  }
  if (i < e) atomicAdd(&deg[dst[i]], 1);
  if (i < 64 * 128) {              // WfcT_g[nc*128+k] = W_fc[k*64+nc]
    int nc = i >> 7, k = i & 127;
    WfcT_g[i] = f2bf(W_fc[k * 64 + nc]);
  }
  if (i < 64 * 64) {               // WresT_g[nc*64+k] = W_res[k*64+nc]
    int nc = i >> 6, k = i & 63;
    WresT_g[i] = f2bf(W_res[k * 64 + nc]);
  }
}

// ---- scan step 1: per-block exclusive scan of deg -> offsets, block sums ----
__global__ void k_scan1(const int* __restrict__ deg, int* __restrict__ offsets,
                        int* __restrict__ blksum, int n) {
  __shared__ int sc[256];
  int t = threadIdx.x;
  int i = blockIdx.x * 256 + t;
  int d = (i < n) ? deg[i] : 0;
  sc[t] = d;
  __syncthreads();
  for (int off = 1; off < 256; off <<= 1) {
    int v = (t >= off) ? sc[t - off] : 0;
    __syncthreads();
    sc[t] += v;
    __syncthreads();
  }
  if (i < n) offsets[i] = sc[t] - d;
  if (t == 255) blksum[blockIdx.x] = sc[255];
}

// ---- scan step 2: each block redundantly reduces blksum[0..bid) and adds ----
__global__ void k_scan2b(int* __restrict__ offsets, const int* __restrict__ blksum,
                         int n, int e) {
  const int bid = blockIdx.x, t = threadIdx.x;
  int v = 0;
  for (int j = t; j < bid; j += 256) v += blksum[j];
  v += __shfl_xor(v, 32); v += __shfl_xor(v, 16); v += __shfl_xor(v, 8);
  v += __shfl_xor(v, 4);  v += __shfl_xor(v, 2);  v += __shfl_xor(v, 1);
  __shared__ int red[4];
  if ((t & 63) == 0) red[t >> 6] = v;
  __syncthreads();
  int pre = red[0] + red[1] + red[2] + red[3];
  int i = bid * 256 + t;
  if (i < n) offsets[i] += pre;
  if (bid == (int)gridDim.x - 1 && t == 0) offsets[n] = e;
}

// ---- CSR fill: reuse deg as cursor via atomicSub (deg dead afterwards) ----
__global__ void k_fill(const int* __restrict__ src, const int* __restrict__ dst,
                       const int* __restrict__ offsets, int* __restrict__ deg,
                       int* __restrict__ csr, int e) {
  int i = blockIdx.x * blockDim.x + threadIdx.x;
  if (i < e) {
    int d = dst[i];
    int p = atomicSub(&deg[d], 1);       // returns old value in [1, deg]
    csr[offsets[d] + p - 1] = src[i];
  }
}

// ---- fused main: 64-node tile per block, 4 waves ----
// LDS strides (shorts) for conflict-free-in-throughput ds accesses:
//   XT_S=72 (36 dwords), WF_S=136 (68 dwords) -> (m+quad)%8 uniform spread.
#define XT_S 72
#define WF_S 136

__global__ __launch_bounds__(256, 4) void k_main(
    const unsigned short* __restrict__ xb,
    const int* __restrict__ offsets, const int* __restrict__ csr,
    const unsigned short* __restrict__ WfcT_g,
    const unsigned short* __restrict__ WresT_g,
    const float* __restrict__ b_fc, const float* __restrict__ b_res,
    float* __restrict__ out, int n) {
  __shared__ unsigned short Mt[64 * XT_S];     // mean tile, bf16 (9.2 KB)
  __shared__ unsigned short WfcT[64 * WF_S];   // W_fc^T padded (17.4 KB)
  __shared__ unsigned short WresT[64 * XT_S];  // W_res^T padded (9.2 KB)

  const int tid = threadIdx.x;
  const int tile0 = blockIdx.x * 64;

  // Stage W^T bf16 global -> padded LDS, 16B vector ops.
  for (int c0 = tid; c0 < 1024; c0 += 256) {   // 8192 shorts / 8
    int nc = c0 >> 4, kc = (c0 & 15) << 3;
    *(uint4*)(&WfcT[nc * WF_S + kc]) = ((const uint4*)WfcT_g)[c0];
  }
  for (int c0 = tid; c0 < 512; c0 += 256) {    // 4096 shorts / 8
    int nc = c0 >> 3, kc = (c0 & 7) << 3;
    *(uint4*)(&WresT[nc * XT_S + kc]) = ((const uint4*)WresT_g)[c0];
  }

  // ---- gather: thread -> (node nd, 16-feature chunk c). 64 nodes in flight.
  {
    const int nd = tid >> 2;
    const int c = tid & 3;
    const int node = tile0 + nd;
    float s[16];
#pragma unroll
    for (int k = 0; k < 16; ++k) s[k] = 0.f;
    int dg = 0;
    if (node < n) {
      const int o0 = offsets[node];
      const int o1 = offsets[node + 1];
      dg = o1 - o0;
      int nxt = (dg > 0) ? csr[o0] : 0;
      for (int j = 0; j < dg; ++j) {
        const int sidx = nxt;
        if (j + 1 < dg) nxt = csr[o0 + j + 1];   // prefetch next index
        const uint4* rp = (const uint4*)(xb + (size_t)sidx * 64 + c * 16);
        const uint4 u0 = rp[0];
        const uint4 u1 = rp[1];
#define ACC2(u, k0)                                             \
        { unsigned int uu = (u);                                \
          s[k0]     += __uint_as_float(uu << 16);               \
          s[k0 + 1] += __uint_as_float(uu & 0xFFFF0000u); }
        ACC2(u0.x, 0)  ACC2(u0.y, 2)  ACC2(u0.z, 4)  ACC2(u0.w, 6)
        ACC2(u1.x, 8)  ACC2(u1.y, 10) ACC2(u1.z, 12) ACC2(u1.w, 14)
#undef ACC2
      }
    }
    const float inv = 1.0f / fmaxf((float)dg, 1.0f);
    unsigned int pk[8];
#pragma unroll
    for (int q = 0; q < 8; ++q)
      pk[q] = (unsigned int)f2bf(s[2 * q] * inv) |
              ((unsigned int)f2bf(s[2 * q + 1] * inv) << 16);
    uint4 w0 = {pk[0], pk[1], pk[2], pk[3]};
    uint4 w1 = {pk[4], pk[5], pk[6], pk[7]};
    *(uint4*)(&Mt[nd * XT_S + c * 16]) = w0;
    *(uint4*)(&Mt[nd * XT_S + c * 16 + 8]) = w1;
  }
  __syncthreads();

  // ---- MFMA phase: wave w computes rows w*16..+15 x all 64 cols ----
  const int lane = tid & 63;
  const int w = tid >> 6;
  const int quad = lane >> 4;
  const int m = lane & 15;
  const int arow = (w << 4) + m;
  const int anode = tile0 + arow;

  // A(X) fragments straight from global (coalesced: wave covers 2KB contig).
  bf16x8 aX0 = {}, aX1 = {};
  if (anode < n) {
    aX0 = *(const bf16x8*)(xb + (size_t)anode * 64 + quad * 8);
    aX1 = *(const bf16x8*)(xb + (size_t)anode * 64 + 32 + quad * 8);
  }
  bf16x8 aM0 = *(const bf16x8*)(&Mt[arow * XT_S + quad * 8]);
  bf16x8 aM1 = *(const bf16x8*)(&Mt[arow * XT_S + 32 + quad * 8]);

  f32x4 accu[4], accv[4];
#pragma unroll
  for (int nt = 0; nt < 4; ++nt) {
    const int nc = nt * 16 + m;
    bf16x8 b0 = *(const bf16x8*)(&WfcT[nc * WF_S + quad * 8]);
    bf16x8 b1 = *(const bf16x8*)(&WfcT[nc * WF_S + 32 + quad * 8]);
    bf16x8 b2 = *(const bf16x8*)(&WfcT[nc * WF_S + 64 + quad * 8]);
    bf16x8 b3 = *(const bf16x8*)(&WfcT[nc * WF_S + 96 + quad * 8]);
    f32x4 acc = {0.f, 0.f, 0.f, 0.f};
    acc = __builtin_amdgcn_mfma_f32_16x16x32_bf16(aX0, b0, acc, 0, 0, 0);
    acc = __builtin_amdgcn_mfma_f32_16x16x32_bf16(aX1, b1, acc, 0, 0, 0);
    acc = __builtin_amdgcn_mfma_f32_16x16x32_bf16(aM0, b2, acc, 0, 0, 0);
    acc = __builtin_amdgcn_mfma_f32_16x16x32_bf16(aM1, b3, acc, 0, 0, 0);
    accu[nt] = acc;
    bf16x8 c0 = *(const bf16x8*)(&WresT[nc * XT_S + quad * 8]);
    bf16x8 c1 = *(const bf16x8*)(&WresT[nc * XT_S + 32 + quad * 8]);
    f32x4 accr = {0.f, 0.f, 0.f, 0.f};
    accr = __builtin_amdgcn_mfma_f32_16x16x32_bf16(aX0, c0, accr, 0, 0, 0);
    accr = __builtin_amdgcn_mfma_f32_16x16x32_bf16(aX1, c1, accr, 0, 0, 0);
    accv[nt] = accr;
  }

  // ---- epilogue: C/D layout col=lane&15, row=quad*4+reg ----
#pragma unroll
  for (int nt = 0; nt < 4; ++nt) {
    const int nc = nt * 16 + m;
    const float bf = b_fc[nc];
    const float br = b_res[nc];
#pragma unroll
    for (int r = 0; r < 4; ++r) {
      int lr = (w << 4) + (quad << 2) + r;
      int node = tile0 + lr;
      if (node < n) {
        float u = fmaxf(accu[nt][r] + bf, 0.f);
        out[node * 64 + nc] = u + accv[nt][r] + br;
      }
    }
  }
}

extern "C" void kernel_launch(void* const* d_in, const int* in_sizes, int n_in,
                              void* d_out, int out_size, void* d_ws, size_t ws_size,
                              hipStream_t stream) {
  const float* x = (const float*)d_in[0];
  const int* src = (const int*)d_in[1];
  const int* dst = (const int*)d_in[2];
  const float* W_fc = (const float*)d_in[3];
  const float* b_fc = (const float*)d_in[4];
  const float* W_res = (const float*)d_in[5];
  const float* b_res = (const float*)d_in[6];
  float* out = (float*)d_out;
  const int n = in_sizes[0] / 64;
  const int e = in_sizes[1];

  // workspace layout (~16.9 MB); 16B-aligned vector regions first
  char* p = (char*)d_ws;
  unsigned short* xb = (unsigned short*)p;      p += (size_t)n * 64 * 2;
  unsigned short* WfcT_g = (unsigned short*)p;  p += 64 * 128 * 2;
  unsigned short* WresT_g = (unsigned short*)p; p += 64 * 64 * 2;
  int* deg = (int*)p;                           p += (size_t)n * 4;
  int* offsets = (int*)p;                       p += (size_t)(n + 1) * 4;
  p = (char*)(((uintptr_t)p + 15) & ~(uintptr_t)15);
  int* blksum = (int*)p;                        p += 4096;
  int* csr = (int*)p;

  hipMemsetAsync(deg, 0, (size_t)n * 4, stream);

  const int total4 = in_sizes[0] / 4;
  const int prep_n = (total4 > e) ? total4 : e;
  k_prep<<<(prep_n + 255) / 256, 256, 0, stream>>>(x, xb, total4, dst, deg, e,
                                                   W_fc, WfcT_g, W_res, WresT_g);
  const int nblk = (n + 255) / 256;
  k_scan1<<<nblk, 256, 0, stream>>>(deg, offsets, blksum, n);
  k_scan2b<<<nblk, 256, 0, stream>>>(offsets, blksum, n, e);
  k_fill<<<(e + 255) / 256, 256, 0, stream>>>(src, dst, offsets, deg, csr, e);
  k_main<<<(n + 63) / 64, 256, 0, stream>>>(xb, offsets, csr, WfcT_g, WresT_g,
                                            b_fc, b_res, out, n);
}

// Round 3
// 165.953 us; speedup vs baseline: 1.8357x; 1.1794x over previous
//
#include <hip/hip_runtime.h>
#include <hip/hip_bf16.h>
#include <stdint.h>

// GraphSAGE layer fused pipeline for MI355X (gfx950), round 3.
// memset(deg) | k_prep(cvt+hist+rank+Wcvt) | k_scan1 | k_scan2b | k_fill | k_main

typedef __bf16 bf16x8 __attribute__((ext_vector_type(8)));
typedef float f32x4 __attribute__((ext_vector_type(4)));

__device__ __forceinline__ unsigned short f2bf(float f) {
  unsigned int u = __float_as_uint(f);
  u += 0x7FFFu + ((u >> 16) & 1u);   // RNE
  return (unsigned short)(u >> 16);
}

// ---- fused prep: x->bf16, degree histogram + per-edge rank, W^T -> bf16 ----
__global__ void k_prep(const float* __restrict__ x, unsigned short* __restrict__ xb,
                       int total4,
                       const int* __restrict__ dst, int* __restrict__ deg,
                       int* __restrict__ rank, int e,
                       const float* __restrict__ W_fc, unsigned short* __restrict__ WfcT_g,
                       const float* __restrict__ W_res, unsigned short* __restrict__ WresT_g) {
  int i = blockIdx.x * 256 + threadIdx.x;
  if (i < total4) {
    const float4 v = ((const float4*)x)[i];
    ushort4 o;
    o.x = f2bf(v.x); o.y = f2bf(v.y); o.z = f2bf(v.z); o.w = f2bf(v.w);
    ((ushort4*)xb)[i] = o;
  }
  if (i < e) rank[i] = atomicAdd(&deg[dst[i]], 1);
  if (i < 64 * 128) {              // WfcT_g[nc*128+k] = W_fc[k*64+nc]
    int nc = i >> 7, k = i & 127;
    WfcT_g[i] = f2bf(W_fc[k * 64 + nc]);
  }
  if (i < 64 * 64) {               // WresT_g[nc*64+k] = W_res[k*64+nc]
    int nc = i >> 6, k = i & 63;
    WresT_g[i] = f2bf(W_res[k * 64 + nc]);
  }
}

// ---- scan step 1: per-block exclusive scan of deg -> offsets, block sums ----
__global__ void k_scan1(const int* __restrict__ deg, int* __restrict__ offsets,
                        int* __restrict__ blksum, int n) {
  __shared__ int sc[256];
  int t = threadIdx.x;
  int i = blockIdx.x * 256 + t;
  int d = (i < n) ? deg[i] : 0;
  sc[t] = d;
  __syncthreads();
  for (int off = 1; off < 256; off <<= 1) {
    int v = (t >= off) ? sc[t - off] : 0;
    __syncthreads();
    sc[t] += v;
    __syncthreads();
  }
  if (i < n) offsets[i] = sc[t] - d;
  if (t == 255) blksum[blockIdx.x] = sc[255];
}

// ---- scan step 2: each block redundantly reduces blksum[0..bid) and adds ----
__global__ void k_scan2b(int* __restrict__ offsets, const int* __restrict__ blksum,
                         int n, int e) {
  const int bid = blockIdx.x, t = threadIdx.x;
  int v = 0;
  for (int j = t; j < bid; j += 256) v += blksum[j];
  v += __shfl_xor(v, 32); v += __shfl_xor(v, 16); v += __shfl_xor(v, 8);
  v += __shfl_xor(v, 4);  v += __shfl_xor(v, 2);  v += __shfl_xor(v, 1);
  __shared__ int red[4];
  if ((t & 63) == 0) red[t >> 6] = v;
  __syncthreads();
  int pre = red[0] + red[1] + red[2] + red[3];
  int i = bid * 256 + t;
  if (i < n) offsets[i] += pre;
  if (bid == (int)gridDim.x - 1 && t == 0) offsets[n] = e;
}

// ---- CSR fill: atomic-free, 4 edges per thread for ILP ----
__global__ void k_fill(const int* __restrict__ src, const int* __restrict__ dst,
                       const int* __restrict__ offsets, const int* __restrict__ rank,
                       int* __restrict__ csr, int e) {
  int i4 = (blockIdx.x * 256 + threadIdx.x) * 4;
  if (i4 + 3 < e) {
    const int4 d = *(const int4*)(dst + i4);
    const int4 r = *(const int4*)(rank + i4);
    const int4 s = *(const int4*)(src + i4);
    int p0 = offsets[d.x], p1 = offsets[d.y], p2 = offsets[d.z], p3 = offsets[d.w];
    csr[p0 + r.x] = s.x;
    csr[p1 + r.y] = s.y;
    csr[p2 + r.z] = s.z;
    csr[p3 + r.w] = s.w;
  } else {
    for (int i = i4; i < e; ++i) csr[offsets[dst[i]] + rank[i]] = src[i];
  }
}

// ---- fused main: 64-node tile per block, 4 waves ----
#define XT_S 72
#define WF_S 136

__global__ __launch_bounds__(256, 3) void k_main(
    const unsigned short* __restrict__ xb,
    const int* __restrict__ offsets, const int* __restrict__ csr,
    const unsigned short* __restrict__ WfcT_g,
    const unsigned short* __restrict__ WresT_g,
    const float* __restrict__ b_fc, const float* __restrict__ b_res,
    float* __restrict__ out, int n) {
  __shared__ unsigned short Mt[64 * XT_S];     // mean tile, bf16 (9.2 KB)
  __shared__ unsigned short WfcT[64 * WF_S];   // W_fc^T padded (17.4 KB)
  __shared__ unsigned short WresT[64 * XT_S];  // W_res^T padded (9.2 KB)

  const int tid = threadIdx.x;
  const int tile0 = blockIdx.x * 64;

  // Stage W^T bf16 global -> padded LDS, 16B vector ops.
  for (int c0 = tid; c0 < 1024; c0 += 256) {
    int nc = c0 >> 4, kc = (c0 & 15) << 3;
    *(uint4*)(&WfcT[nc * WF_S + kc]) = ((const uint4*)WfcT_g)[c0];
  }
  for (int c0 = tid; c0 < 512; c0 += 256) {
    int nc = c0 >> 3, kc = (c0 & 7) << 3;
    *(uint4*)(&WresT[nc * XT_S + kc]) = ((const uint4*)WresT_g)[c0];
  }

  // ---- gather: thread -> (node nd, 16-feature chunk c); two independent
  // edge chains per thread, each with dist-1 row / dist-2 index prefetch.
  {
    const int nd = tid >> 2;
    const int c = tid & 3;
    const int node = tile0 + nd;
    float s[16], sb[16];
#pragma unroll
    for (int k = 0; k < 16; ++k) { s[k] = 0.f; sb[k] = 0.f; }
    int dg = 0;
    if (node < n) {
      const int o0 = offsets[node];
      const int o1 = offsets[node + 1];
      dg = o1 - o0;
      if (dg > 0) {
        const int hb = dg >> 1;          // chain B length
        const int ha = dg - hb;          // chain A length (>= hb)
        const int lastA = o0 + ha - 1;
        const int lastE = o1 - 1;
        const unsigned short* __restrict__ xbp = xb;
        // edge-0 indices
        int iA = csr[o0];
        int iB = csr[min(o0 + ha, lastE)];
        // edge-0 rows
        const uint4* pa = (const uint4*)(xbp + (size_t)iA * 64 + c * 16);
        uint4 ra0 = pa[0], ra1 = pa[1];
        const uint4* pb = (const uint4*)(xbp + (size_t)iB * 64 + c * 16);
        uint4 rb0 = pb[0], rb1 = pb[1];
        // edge-1 indices
        int iA1 = csr[min(o0 + 1, lastA)];
        int iB1 = csr[min(o0 + ha + 1, lastE)];
        for (int j = 0; j < ha; ++j) {
          // issue next rows (edge j+1)
          const uint4* na = (const uint4*)(xbp + (size_t)iA1 * 64 + c * 16);
          uint4 qa0 = na[0], qa1 = na[1];
          const uint4* nb = (const uint4*)(xbp + (size_t)iB1 * 64 + c * 16);
          uint4 qb0 = nb[0], qb1 = nb[1];
          // issue next-next indices (edge j+2)
          iA1 = csr[min(o0 + j + 2, lastA)];
          iB1 = csr[min(o0 + ha + j + 2, lastE)];
          // accumulate current rows
#define ACC2(dst_, u, k0)                                       \
          { unsigned int uu = (u);                              \
            dst_[k0]     += __uint_as_float(uu << 16);          \
            dst_[k0 + 1] += __uint_as_float(uu & 0xFFFF0000u); }
          ACC2(s, ra0.x, 0)  ACC2(s, ra0.y, 2)  ACC2(s, ra0.z, 4)  ACC2(s, ra0.w, 6)
          ACC2(s, ra1.x, 8)  ACC2(s, ra1.y, 10) ACC2(s, ra1.z, 12) ACC2(s, ra1.w, 14)
          if (j < hb) {
            ACC2(sb, rb0.x, 0)  ACC2(sb, rb0.y, 2)  ACC2(sb, rb0.z, 4)  ACC2(sb, rb0.w, 6)
            ACC2(sb, rb1.x, 8)  ACC2(sb, rb1.y, 10) ACC2(sb, rb1.z, 12) ACC2(sb, rb1.w, 14)
          }
#undef ACC2
          ra0 = qa0; ra1 = qa1; rb0 = qb0; rb1 = qb1;
        }
      }
    }
    const float inv = 1.0f / fmaxf((float)dg, 1.0f);
    unsigned int pk[8];
#pragma unroll
    for (int q = 0; q < 8; ++q)
      pk[q] = (unsigned int)f2bf((s[2 * q] + sb[2 * q]) * inv) |
              ((unsigned int)f2bf((s[2 * q + 1] + sb[2 * q + 1]) * inv) << 16);
    uint4 w0 = {pk[0], pk[1], pk[2], pk[3]};
    uint4 w1 = {pk[4], pk[5], pk[6], pk[7]};
    *(uint4*)(&Mt[nd * XT_S + c * 16]) = w0;
    *(uint4*)(&Mt[nd * XT_S + c * 16 + 8]) = w1;
  }
  __syncthreads();

  // ---- MFMA phase: wave w computes rows w*16..+15 x all 64 cols ----
  const int lane = tid & 63;
  const int w = tid >> 6;
  const int quad = lane >> 4;
  const int m = lane & 15;
  const int arow = (w << 4) + m;
  const int anode = tile0 + arow;

  bf16x8 aX0 = {}, aX1 = {};
  if (anode < n) {
    aX0 = *(const bf16x8*)(xb + (size_t)anode * 64 + quad * 8);
    aX1 = *(const bf16x8*)(xb + (size_t)anode * 64 + 32 + quad * 8);
  }
  bf16x8 aM0 = *(const bf16x8*)(&Mt[arow * XT_S + quad * 8]);
  bf16x8 aM1 = *(const bf16x8*)(&Mt[arow * XT_S + 32 + quad * 8]);

  f32x4 accu[4], accv[4];
#pragma unroll
  for (int nt = 0; nt < 4; ++nt) {
    const int nc = nt * 16 + m;
    bf16x8 b0 = *(const bf16x8*)(&WfcT[nc * WF_S + quad * 8]);
    bf16x8 b1 = *(const bf16x8*)(&WfcT[nc * WF_S + 32 + quad * 8]);
    bf16x8 b2 = *(const bf16x8*)(&WfcT[nc * WF_S + 64 + quad * 8]);
    bf16x8 b3 = *(const bf16x8*)(&WfcT[nc * WF_S + 96 + quad * 8]);
    f32x4 acc = {0.f, 0.f, 0.f, 0.f};
    acc = __builtin_amdgcn_mfma_f32_16x16x32_bf16(aX0, b0, acc, 0, 0, 0);
    acc = __builtin_amdgcn_mfma_f32_16x16x32_bf16(aX1, b1, acc, 0, 0, 0);
    acc = __builtin_amdgcn_mfma_f32_16x16x32_bf16(aM0, b2, acc, 0, 0, 0);
    acc = __builtin_amdgcn_mfma_f32_16x16x32_bf16(aM1, b3, acc, 0, 0, 0);
    accu[nt] = acc;
    bf16x8 c0 = *(const bf16x8*)(&WresT[nc * XT_S + quad * 8]);
    bf16x8 c1 = *(const bf16x8*)(&WresT[nc * XT_S + 32 + quad * 8]);
    f32x4 accr = {0.f, 0.f, 0.f, 0.f};
    accr = __builtin_amdgcn_mfma_f32_16x16x32_bf16(aX0, c0, accr, 0, 0, 0);
    accr = __builtin_amdgcn_mfma_f32_16x16x32_bf16(aX1, c1, accr, 0, 0, 0);
    accv[nt] = accr;
  }

  // ---- epilogue: C/D layout col=lane&15, row=quad*4+reg ----
#pragma unroll
  for (int nt = 0; nt < 4; ++nt) {
    const int nc = nt * 16 + m;
    const float bf = b_fc[nc];
    const float br = b_res[nc];
#pragma unroll
    for (int r = 0; r < 4; ++r) {
      int lr = (w << 4) + (quad << 2) + r;
      int node = tile0 + lr;
      if (node < n) {
        float u = fmaxf(accu[nt][r] + bf, 0.f);
        out[node * 64 + nc] = u + accv[nt][r] + br;
      }
    }
  }
}

extern "C" void kernel_launch(void* const* d_in, const int* in_sizes, int n_in,
                              void* d_out, int out_size, void* d_ws, size_t ws_size,
                              hipStream_t stream) {
  const float* x = (const float*)d_in[0];
  const int* src = (const int*)d_in[1];
  const int* dst = (const int*)d_in[2];
  const float* W_fc = (const float*)d_in[3];
  const float* b_fc = (const float*)d_in[4];
  const float* W_res = (const float*)d_in[5];
  const float* b_res = (const float*)d_in[6];
  float* out = (float*)d_out;
  const int n = in_sizes[0] / 64;
  const int e = in_sizes[1];

  // workspace layout (~20 MB); 16B-aligned vector regions first
  char* p = (char*)d_ws;
  unsigned short* xb = (unsigned short*)p;      p += (size_t)n * 64 * 2;
  unsigned short* WfcT_g = (unsigned short*)p;  p += 64 * 128 * 2;
  unsigned short* WresT_g = (unsigned short*)p; p += 64 * 64 * 2;
  int* deg = (int*)p;                           p += (size_t)n * 4;
  int* offsets = (int*)p;                       p += (size_t)(n + 1) * 4;
  p = (char*)(((uintptr_t)p + 15) & ~(uintptr_t)15);
  int* blksum = (int*)p;                        p += 4096;
  int* rank = (int*)p;                          p += (size_t)e * 4;
  int* csr = (int*)p;

  hipMemsetAsync(deg, 0, (size_t)n * 4, stream);

  const int total4 = in_sizes[0] / 4;
  const int prep_n = (total4 > e) ? total4 : e;
  k_prep<<<(prep_n + 255) / 256, 256, 0, stream>>>(x, xb, total4, dst, deg, rank,
                                                   e, W_fc, WfcT_g, W_res, WresT_g);
  const int nblk = (n + 255) / 256;
  k_scan1<<<nblk, 256, 0, stream>>>(deg, offsets, blksum, n);
  k_scan2b<<<nblk, 256, 0, stream>>>(offsets, blksum, n, e);
  k_fill<<<(e / 4 + 255) / 256, 256, 0, stream>>>(src, dst, offsets, rank, csr, e);
  k_main<<<(n + 63) / 64, 256, 0, stream>>>(xb, offsets, csr, WfcT_g, WresT_g,
                                            b_fc, b_res, out, n);
}